// Round 9
// baseline (14439.348 us; speedup 1.0000x reference)
//
#include <hip/hip_runtime.h>
#include <math.h>

#define TT 200
#define NDIM 1024
#define IDIM 128
#define ODIM 128
#define NB 256

// ws float offsets
#define J4_OFF 0          // f32 J4[kq][n][4]: J4[kq*4096 + n*4 + kk] = J[n][4kq+kk]
#define W4_OFF 1048576    // f32 W4[kq][o][4]: W4[kq*512 + o*4 + kk]  = W[o][4kq+kk]
#define SG_OFF 1179648    // f32 Sg[2][256][1024] sigmoid(V), natural layout
#define TH_OFF 1703936    // f32 Th[2][256][1024] tanh(V),  natural layout
#define BAR_OFF 2228224   // u32 cnt[32] @ +0, u32 flg[32] @ +64 (u32 index)

// d_out float offsets
#define VT_STRIDE 205824
#define ZT_BASE   52690944
#define OUTS_BASE 105381888

typedef __attribute__((ext_vector_type(8))) float f32x8;

__global__ __launch_bounds__(256) void rsnn_prologue(
    const float* __restrict__ J, const float* __restrict__ W,
    float* __restrict__ ws, float* __restrict__ out) {
  const int blk = blockIdx.x, tid = threadIdx.x;
  if (blk < 1024) {
    // J4 pack: n = blk, kq = tid
    float4 v = *(const float4*)(J + (size_t)blk * NDIM + (tid << 2));
    *(float4*)(ws + J4_OFF + (size_t)tid * 4096 + (blk << 2)) = v;
  } else if (blk < 1152) {
    // W4 pack: o = blk-1024 (0..127), kq = tid
    const int o = blk - 1024;
    float4 v = *(const float4*)(W + (size_t)o * NDIM + (tid << 2));
    *(float4*)(ws + W4_OFF + (size_t)tid * 512 + (o << 2)) = v;
  } else {
    // init parity-0 state + t=0 output planes + barrier slots
    const int idx = (blk - 1152) * 256 + tid;   // 0..262143
    ws[SG_OFF + idx] = 0.5f;                    // sigmoid(0)
    ws[TH_OFF + idx] = 0.0f;                    // tanh(0)
    const int b = idx >> 10, n = idx & 1023;
    out[(size_t)b * VT_STRIDE + n] = 0.0f;
    out[ZT_BASE + (size_t)b * VT_STRIDE + n] = 0.0f;
    if (idx < 128) ((unsigned*)(ws + BAR_OFF))[idx] = 0u;
  }
}

// Persistent kernel: 512 blocks (bt=blk>>4: 8-batch tile, nt=blk&15: 64-neuron
// tile) x 512 threads = 8 waves (q = w&3: k-chunk, bg = w>>2: 4-batch group).
// S operand via wave-uniform same-address f32x8 global loads (no LDS pipe).
// Per-bt group barrier (16 contiguous blocks) between steps.
// Bit-exact R1 chains: per (b,n) k-chunks {0-287,288-575,576-863,864-1023+input},
// reduce ((p0+p1)+p2)+p3; outs 4x256-k chains, ((0+1)+2)+3; verbatim epilogue.
__global__ __launch_bounds__(512, 4) void rsnn_persist(
    const float* __restrict__ inputs, const float* __restrict__ noise,
    const float* __restrict__ Bm,
    float* __restrict__ ws, float* __restrict__ out) {
  const int tid = threadIdx.x;
  const int l = tid & 63;
  const int w = __builtin_amdgcn_readfirstlane(tid >> 6);  // 0..7
  const int q = w & 3, bg = w >> 2;
  const int bt = blockIdx.x >> 4, nt = blockIdx.x & 15;
  const int b0 = bt << 3;
  const int nl = (nt << 6) + l;          // global n for this lane
  const int nl4 = nl << 2;

  const float* J4 = ws + J4_OFF;
  const float* W4 = ws + W4_OFF;
  float* Sg = ws + SG_OFF;
  float* Th = ws + TH_OFF;
  unsigned* cnt = (unsigned*)(ws + BAR_OFF) + bt;
  unsigned* flg = (unsigned*)(ws + BAR_OFF) + 64 + bt;

  __shared__ float B_lds[64 * 130];      // B[n_local][i], pad 130 (2-way free)
  __shared__ float redS[4][8][64];
  __shared__ float red2[4][64];

  // fill B_lds once: B natural (1024 n x 128 i)
  for (int idx = tid; idx < 64 * IDIM; idx += 512) {
    const int n = idx >> 7, i = idx & 127;
    B_lds[n * 130 + i] = Bm[(size_t)((nt << 6) + n) * IDIM + i];
  }
  __syncthreads();

  float vreg = 0.f;                      // V for cell (b0+bb, n0+nn)
  const int bb = tid >> 6, nn = tid & 63;

  for (int s = 0; s <= TT; ++s) {
    if (s) {
      // ---- per-bt group barrier (16 blocks), R8-proven protocol ----
      __syncthreads();
      if (tid == 0) {
        __threadfence();
        unsigned prev = __hip_atomic_fetch_add(cnt, 1u, __ATOMIC_RELAXED,
                                               __HIP_MEMORY_SCOPE_AGENT);
        if (prev == 15u) {
          __hip_atomic_store(cnt, 0u, __ATOMIC_RELAXED, __HIP_MEMORY_SCOPE_AGENT);
          __hip_atomic_store(flg, (unsigned)s, __ATOMIC_RELEASE,
                             __HIP_MEMORY_SCOPE_AGENT);
        } else {
          while (__hip_atomic_load(flg, __ATOMIC_RELAXED,
                                   __HIP_MEMORY_SCOPE_AGENT) < (unsigned)s)
            __builtin_amdgcn_s_sleep(1);
        }
        __threadfence();
      }
      __syncthreads();
    }

    if (s < TT) {
      // ---- P1: recurrent partial for chunk q, batches bg*4..bg*4+3 ----
      const float* Sp = Sg + (size_t)(s & 1) * (NB * NDIM);
      const float* Sb0 = Sp + (size_t)(b0 + (bg << 2) + 0) * NDIM;
      const float* Sb1 = Sp + (size_t)(b0 + (bg << 2) + 1) * NDIM;
      const float* Sb2 = Sp + (size_t)(b0 + (bg << 2) + 2) * NDIM;
      const float* Sb3 = Sp + (size_t)(b0 + (bg << 2) + 3) * NDIM;
      float a0 = 0.f, a1 = 0.f, a2 = 0.f, a3 = 0.f;
      const int k0 = q * 288;
      const int k1 = (q < 3) ? (k0 + 288) : NDIM;   // q=3: [864,1024)
#pragma unroll 2
      for (int kb = k0; kb < k1; kb += 8) {
        f32x8 s0 = *(const f32x8*)(Sb0 + kb);   // wave-uniform same-addr loads
        f32x8 s1 = *(const f32x8*)(Sb1 + kb);
        f32x8 s2 = *(const f32x8*)(Sb2 + kb);
        f32x8 s3 = *(const f32x8*)(Sb3 + kb);
        float4 ja = *(const float4*)(J4 + (size_t)(kb >> 2) * 4096 + nl4);
        float4 jb = *(const float4*)(J4 + (size_t)((kb >> 2) + 1) * 4096 + nl4);
#define JSTEP(kk, jv) \
        a0 = fmaf(s0[kk], jv, a0); a1 = fmaf(s1[kk], jv, a1); \
        a2 = fmaf(s2[kk], jv, a2); a3 = fmaf(s3[kk], jv, a3);
        JSTEP(0, ja.x) JSTEP(1, ja.y) JSTEP(2, ja.z) JSTEP(3, ja.w)
        JSTEP(4, jb.x) JSTEP(5, jb.y) JSTEP(6, jb.z) JSTEP(7, jb.w)
#undef JSTEP
      }
      if (q == 3) {  // input projection appended to chunk-3 chain (R1 order)
        const float* Xb0 = inputs + ((size_t)(b0 + (bg << 2) + 0) * TT + s) * IDIM;
        const float* Xb1 = inputs + ((size_t)(b0 + (bg << 2) + 1) * TT + s) * IDIM;
        const float* Xb2 = inputs + ((size_t)(b0 + (bg << 2) + 2) * TT + s) * IDIM;
        const float* Xb3 = inputs + ((size_t)(b0 + (bg << 2) + 3) * TT + s) * IDIM;
#pragma unroll 2
        for (int ib = 0; ib < IDIM; ib += 8) {
          f32x8 x0 = *(const f32x8*)(Xb0 + ib);
          f32x8 x1 = *(const f32x8*)(Xb1 + ib);
          f32x8 x2 = *(const f32x8*)(Xb2 + ib);
          f32x8 x3 = *(const f32x8*)(Xb3 + ib);
#define ISTEP(kk) { float bv = B_lds[l * 130 + ib + kk]; \
        a0 = fmaf(x0[kk], bv, a0); a1 = fmaf(x1[kk], bv, a1); \
        a2 = fmaf(x2[kk], bv, a2); a3 = fmaf(x3[kk], bv, a3); }
          ISTEP(0) ISTEP(1) ISTEP(2) ISTEP(3)
          ISTEP(4) ISTEP(5) ISTEP(6) ISTEP(7)
#undef ISTEP
        }
      }
      redS[q][(bg << 2) + 0][l] = a0;
      redS[q][(bg << 2) + 1][l] = a1;
      redS[q][(bg << 2) + 2][l] = a2;
      redS[q][(bg << 2) + 3][l] = a3;
    }

    if (s >= 1 && w < 4) {
      // ---- P1b: outs partial for t = s-1, chunk q=w; lane = (b2, o) ----
      const float* Thp = Th + (size_t)(s & 1) * (NB * NDIM);
      const int b2 = l >> 3, oo = l & 7;
      const int og = (nt << 3) + oo;
      const float* trow = Thp + (size_t)(b0 + b2) * NDIM;
      float acco = 0.f;
      const int kob = q << 8;
#pragma unroll 4
      for (int k = kob; k < kob + 256; k += 4) {
        float4 tq = *(const float4*)(trow + k);
        float4 wq = *(const float4*)(W4 + (size_t)(k >> 2) * 512 + (og << 2));
        acco = fmaf(tq.x, wq.x, acco);
        acco = fmaf(tq.y, wq.y, acco);
        acco = fmaf(tq.z, wq.z, acco);
        acco = fmaf(tq.w, wq.w, acco);
      }
      red2[q][l] = acco;
    }
    __syncthreads();

    if (s < TT) {
      // ---- P3: merge + epilogue, one cell (bb, nn) per thread ----
      float sum = ((redS[0][bb][nn] + redS[1][bb][nn]) + redS[2][bb][nn]) +
                  redS[3][bb][nn];
      const int b = b0 + bb;
      const int ng = (nt << 6) + nn;
      float vnew = 0.9f * vreg + 0.1f * sum;
      vreg = vnew;
      out[(size_t)b * VT_STRIDE + (size_t)(s + 1) * NDIM + ng] = vnew;
      float sg = 1.0f / (1.0f + expf(-vnew));
      const int p = (s + 1) & 1;
      Sg[(size_t)p * (NB * NDIM) + (size_t)b * NDIM + ng] = sg;
      Th[(size_t)p * (NB * NDIM) + (size_t)b * NDIM + ng] = tanhf(vnew);
      float zarg = (0.1f * (vnew - 0.4f)) / 0.4f;
      float zs = 1.0f / (1.0f + expf(-zarg));
      float u = noise[((size_t)b * TT + s) * NDIM + ng];
      out[ZT_BASE + (size_t)b * VT_STRIDE + (size_t)(s + 1) * NDIM + ng] =
          (zs > u) ? 1.0f : 0.0f;
    }

    if (s >= 1 && tid < 64) {
      // ---- P3b: outs merge + store ----
      float sum2 = ((red2[0][tid] + red2[1][tid]) + red2[2][tid]) + red2[3][tid];
      const int b2 = tid >> 3, oo = tid & 7;
      out[OUTS_BASE + ((size_t)(b0 + b2) * TT + (s - 1)) * ODIM + (nt << 3) + oo] =
          sum2;
    }
  }
}

extern "C" void kernel_launch(void* const* d_in, const int* in_sizes, int n_in,
                              void* d_out, int out_size, void* d_ws, size_t ws_size,
                              hipStream_t stream) {
  const float* inputs = (const float*)d_in[0];  // (256,200,128)
  const float* noise  = (const float*)d_in[1];  // (256,200,1024)
  const float* J      = (const float*)d_in[2];  // (1024,1024)
  const float* Bm     = (const float*)d_in[3];  // (1024,128)
  const float* W      = (const float*)d_in[4];  // (128,1024)
  float* out = (float*)d_out;
  float* ws  = (float*)d_ws;

  rsnn_prologue<<<2176, 256, 0, stream>>>(J, W, ws, out);
  rsnn_persist<<<512, 512, 0, stream>>>(inputs, noise, Bm, ws, out);
}